// Round 1
// 750.428 us; speedup vs baseline: 1.0419x; 1.0419x over previous
//
#include <hip/hip_runtime.h>
#include <hip/hip_bf16.h>
#include <stdint.h>

#define N_NODES 50000
#define E_EDGES 400000
#define K1H 4
#define D_IN 1280
#define H_OUT 256
#define NTOT 1024          // K1H * H_OUT (fused GEMM output width)
#define MP 50176           // N padded to 196 row-tiles of 256
#define CAP 128            // edge bucket capacity per dest row (lambda=32, overflow ~e^-60)

typedef float f32x4 __attribute__((ext_vector_type(4)));
typedef short s16x8 __attribute__((ext_vector_type(8)));

#define GLOBAL_AS __attribute__((address_space(1)))
#define LDS_AS __attribute__((address_space(3)))

__device__ __forceinline__ void g2lds16(const void* g, void* l) {
    __builtin_amdgcn_global_load_lds((const GLOBAL_AS uint32_t*)g,
                                     (LDS_AS uint32_t*)l, 16, 0, 0);
}

// fp32 -> bf16 round-nearest-even
__device__ __forceinline__ ushort f2bf(float x) {
    uint32_t u = __float_as_uint(x);
    uint32_t r = u + 0x7FFFu + ((u >> 16) & 1u);
    return (ushort)(r >> 16);
}
__device__ __forceinline__ float bf2f(ushort u) {
    return __uint_as_float(((uint32_t)u) << 16);
}

// ---- Kernel 1a: X fp32 [N,D] -> Xb bf16 [MP,D], pad rows zeroed ----
__global__ void cvtX_kernel(const float* __restrict__ X, ushort* __restrict__ Xb) {
    int i = (blockIdx.x * 256 + threadIdx.x) * 4;   // MP*D_IN = 64,225,280 < 2^31
    ushort4 o;
    if (i < N_NODES * D_IN) {
        const float4 v = *(const float4*)(X + i);
        o.x = f2bf(v.x); o.y = f2bf(v.y); o.z = f2bf(v.z); o.w = f2bf(v.w);
    } else {
        o.x = 0; o.y = 0; o.z = 0; o.w = 0;
    }
    *(ushort4*)(Xb + i) = o;
}

// ---- Kernel 1b: W [4][1280][256] fp32 -> WbT bf16 [n=k*256+h][d] (B^T layout) ----
__global__ void cvtW_kernel(const float* __restrict__ W, ushort* __restrict__ WbT) {
    int o = blockIdx.x * 256 + threadIdx.x;
    if (o >= NTOT * D_IN) return;
    int n = o / D_IN, d = o - n * D_IN;
    int k = n >> 8, h = n & 255;
    WbT[o] = f2bf(W[(k * D_IN + d) * H_OUT + h]);
}

// ---- Kernel 2: single-pass bucket scatter.  edge record = (Yb offset, val) ----
__global__ void scatter_kernel(const int* __restrict__ rows, const int* __restrict__ cols,
                               const float* __restrict__ vals, int* __restrict__ cnt,
                               int2* __restrict__ edges) {
    int i = blockIdx.x * 256 + threadIdx.x;
    if (i >= K1H * E_EDGES) return;
    int k = i / E_EDGES;                     // hop index 0..3
    int r = rows[i];
    int pos = atomicAdd(&cnt[r], 1);
    if (pos < CAP)                           // statistically never taken
        edges[(size_t)r * CAP + pos] =
            make_int2((cols[i] << 10) | (k << 8), __float_as_int(vals[i]));
}

// ---- Kernel 3: GEMM  Yb[MP,1024] = Xb[MP,1280] @ WbT^T  (bf16 MFMA, bf16 out) ----
// 256x256 tile, BK=64, 8 waves (2Mx4N, 128x64 per wave), 8-phase schedule with
// double-buffered LDS (128 KiB) and COUNTED vmcnt (never 0 in main loop): loads
// for tiles t+1/t+2 stay in flight across barriers while MFMA runs (T3+T4+T5).
// Staging-unit geometry matches read geometry so every global_load_lds lands in
// a region whose last ds_read completed >=1 barrier earlier:
//   A unit g = rows [g*64,g*64+64) U [128+g*64,...)   (matches wm x mh reads)
//   B unit g = 32-col stripes q*64+g*32               (matches wn x nh reads)
// XOR chunk swizzle (kc' = kc ^ (row&7)) retained -> 0 bank conflicts.
#define BARR() __builtin_amdgcn_s_barrier()
#define LGKM0() { asm volatile("s_waitcnt lgkmcnt(0)" ::: "memory"); \
                  __builtin_amdgcn_sched_barrier(0); }
#define VMC(N) asm volatile("s_waitcnt vmcnt(" #N ")" ::: "memory")

__global__ void __launch_bounds__(512, 2)
gemm_kernel(const ushort* __restrict__ Xb, const ushort* __restrict__ WbT,
            ushort* __restrict__ Yb) {
    __shared__ ushort lds[2][2][256 * 64];   // [dbuf][A=0,B=1][row*8+chunk], 128 KiB

    const int bid = blockIdx.x;               // 0 .. 783 (196 row-tiles x 4 col-tiles)
    const int xcd = bid & 7, j = bid >> 3;    // 98 blocks per XCD, contiguous tiles
    const int j2 = xcd * 98 + j;
    const int rt = j2 >> 2, ct = j2 & 3;
    const int rowBase = rt * 256, colBase = ct * 256;
    const int t = threadIdx.x;
    const int w = t >> 6, lane = t & 63;
    const int quad = lane >> 4, l16 = lane & 15;
    const int wm = w >> 2, wn = w & 3;        // 2 x 4 wave grid

    f32x4 acc[8][4] = {};
    s16x8 af[4][2];          // A frags, current mh half (reused across 2 phases)
    s16x8 bfr[2][2][2];      // B frags [nh][nt][ks], both halves held per tile

    const int kcg = (t & 7) ^ ((t >> 3) & 7);
    const ushort* pA = Xb + (rowBase + (t >> 3)) * D_IN + kcg * 8;
    const ushort* pB = WbT + (colBase + (t >> 3) + wm * 32) * D_IN + kcg * 8;

    // stage one 16KB half-tile (2 x global_load_lds per thread); LDS dst is
    // lane-linear (base + lane*16) as required by global_load_lds.
#define STAGE_A(BUF, G, KT) { _Pragma("unroll") \
    for (int r = 0; r < 2; ++r) \
        g2lds16(pA + (r * 128 + (G) * 64) * D_IN + (KT) * 64, \
                &lds[BUF][0][(t + (G) * 512 + r * 1024) * 8]); }
#define STAGE_B(BUF, G, KT) { _Pragma("unroll") \
    for (int r = 0; r < 2; ++r) \
        g2lds16(pB + (r * 128 + (G) * 32) * D_IN + (KT) * 64, \
                &lds[BUF][1][(t + wm * 256 + (G) * 256 + r * 1024) * 8]); }
#define LDA_F(BUF, MH) { _Pragma("unroll") \
    for (int mt = 0; mt < 4; ++mt) { \
        const int m = wm * 128 + (MH) * 64 + mt * 16 + l16; \
        _Pragma("unroll") for (int ks = 0; ks < 2; ++ks) \
            af[mt][ks] = *(const s16x8*)&lds[BUF][0][(m * 8 + ((ks * 4 + quad) ^ (l16 & 7))) * 8]; } }
#define LDB_F(BUF, NH) { _Pragma("unroll") \
    for (int nt = 0; nt < 2; ++nt) { \
        const int n = wn * 64 + (NH) * 32 + nt * 16 + l16; \
        _Pragma("unroll") for (int ks = 0; ks < 2; ++ks) \
            bfr[NH][nt][ks] = *(const s16x8*)&lds[BUF][1][(n * 8 + ((ks * 4 + quad) ^ (l16 & 7))) * 8]; } }
#define MMA_Q(MH, NH) { __builtin_amdgcn_s_setprio(1); \
    _Pragma("unroll") for (int mt = 0; mt < 4; ++mt) \
        _Pragma("unroll") for (int nt = 0; nt < 2; ++nt) \
            _Pragma("unroll") for (int ks = 0; ks < 2; ++ks) \
                acc[(MH) * 4 + mt][(NH) * 2 + nt] = \
                    __builtin_amdgcn_mfma_f32_16x16x32_bf16(af[mt][ks], bfr[NH][nt][ks], \
                        acc[(MH) * 4 + mt][(NH) * 2 + nt], 0, 0, 0); \
    __builtin_amdgcn_s_setprio(0); }

    // prologue: tile0 (4 units -> buf0) + tile1 Ag0,Bg0 (-> buf1); wait only for
    // tile0's first two units (4 half-tiles stay in flight), then barrier.
    STAGE_A(0, 0, 0); STAGE_B(0, 0, 0); STAGE_A(0, 1, 0); STAGE_B(0, 1, 0);
    STAGE_A(1, 0, 1); STAGE_B(1, 0, 1);
    VMC(8);
    BARR();

    // main loop: iter i computes tiles 2i (buf0, ph1-4) and 2i+1 (buf1, ph5-8).
    // stage issue order/unit: ph1 tb.Ag1, ph2 tb.Bg1, ph3 ta'.Ag0, ph4 ta'.Bg0,
    // ph5 ta'.Ag1, ph6 ta'.Bg1, ph7 tb'.Ag0, ph8 tb'.Bg0  (ta'=2i+2, tb'=2i+3).
    // counted waits: VMC(6)@ph1 covers ph2/ph3 reads, VMC(8)@ph4 covers ph5,
    // VMC(6)@ph5 covers ph6/ph7, VMC(8)@ph8 covers next ph1 — each followed by a
    // barrier before the protected cross-wave ds_read.
#pragma unroll 1
    for (int i = 0; i < 9; ++i) {
        const int kt0 = 2 * i;
        LDA_F(0, 0); LDB_F(0, 0); STAGE_A(1, 1, kt0 + 1); VMC(6);      // ph1
        BARR(); LGKM0(); MMA_Q(0, 0); BARR();
        LDB_F(0, 1); STAGE_B(1, 1, kt0 + 1);                           // ph2
        BARR(); LGKM0(); MMA_Q(0, 1); BARR();
        LDA_F(0, 1); STAGE_A(0, 0, kt0 + 2);                           // ph3
        BARR(); LGKM0(); MMA_Q(1, 0); BARR();
        STAGE_B(0, 0, kt0 + 2); VMC(8);                                // ph4
        BARR(); MMA_Q(1, 1); BARR();
        LDA_F(1, 0); LDB_F(1, 0); STAGE_A(0, 1, kt0 + 2); VMC(6);      // ph5
        BARR(); LGKM0(); MMA_Q(0, 0); BARR();
        LDB_F(1, 1); STAGE_B(0, 1, kt0 + 2);                           // ph6
        BARR(); LGKM0(); MMA_Q(0, 1); BARR();
        LDA_F(1, 1); STAGE_A(1, 0, kt0 + 3);                           // ph7
        BARR(); LGKM0(); MMA_Q(1, 0); BARR();
        STAGE_B(1, 0, kt0 + 3); VMC(8);                                // ph8
        BARR(); MMA_Q(1, 1); BARR();
    }

    // tail iteration: tiles 18 (buf0) and 19 (buf1); only t19.Ag1/Bg1 still need
    // staging (ph1/ph2); waits tighten since no further prefetch follows.
    LDA_F(0, 0); LDB_F(0, 0); STAGE_A(1, 1, 19); VMC(6);               // ph1
    BARR(); LGKM0(); MMA_Q(0, 0); BARR();
    LDB_F(0, 1); STAGE_B(1, 1, 19);                                    // ph2
    BARR(); LGKM0(); MMA_Q(0, 1); BARR();
    LDA_F(0, 1);                                                       // ph3
    BARR(); LGKM0(); MMA_Q(1, 0); BARR();
    VMC(4);                                                            // ph4
    BARR(); MMA_Q(1, 1); BARR();
    LDA_F(1, 0); LDB_F(1, 0); VMC(0);                                  // ph5
    BARR(); LGKM0(); MMA_Q(0, 0); BARR();
    LDB_F(1, 1);                                                       // ph6
    BARR(); LGKM0(); MMA_Q(0, 1); BARR();
    LDA_F(1, 1);                                                       // ph7
    BARR(); LGKM0(); MMA_Q(1, 0); BARR();
    MMA_Q(1, 1);                                                       // ph8

    // C/D layout: col = lane&15, row = quad*4 + reg  (m89/m91 verified)
    #pragma unroll
    for (int mh = 0; mh < 2; ++mh)
      #pragma unroll
      for (int mt = 0; mt < 4; ++mt)
        #pragma unroll
        for (int nh = 0; nh < 2; ++nh)
          #pragma unroll
          for (int nt = 0; nt < 2; ++nt) {
            const int rr = rowBase + wm * 128 + mh * 64 + mt * 16 + quad * 4;
            const int cc = colBase + wn * 64 + nh * 32 + nt * 16 + l16;
            #pragma unroll
            for (int r = 0; r < 4; ++r)
                Yb[(rr + r) * NTOT + cc] = f2bf(acc[mh * 4 + mt][nh * 2 + nt][r]);
          }
}

#undef STAGE_A
#undef STAGE_B
#undef LDA_F
#undef LDB_F
#undef MMA_Q

// ---- Kernel 4: bucket gather-SpMM + bias + PReLU.  One WAVE per dest row ----
// Lane l holds h = l*4 .. l*4+3; per edge one coalesced 512B ushort4 slice load.
__global__ void __launch_bounds__(256)
spmm_kernel(const int2* __restrict__ edges, const int* __restrict__ cnt,
            const ushort* __restrict__ Yb, const float* __restrict__ b,
            const float* __restrict__ alpha, float* __restrict__ out) {
    const int wid = threadIdx.x >> 6, lane = threadIdx.x & 63;
    const int row = blockIdx.x * 4 + wid;          // N_NODES = 12500 * 4 exactly
    const int h0 = lane * 4;

    float4 acc = make_float4(0.f, 0.f, 0.f, 0.f);
    #pragma unroll
    for (int k = 0; k < K1H; ++k) {
        const float4 bb = *(const float4*)(b + k * H_OUT + h0);
        acc.x += bb.x; acc.y += bb.y; acc.z += bb.z; acc.w += bb.w;
    }

    const int2* eb = edges + (size_t)row * CAP;
    int e = cnt[row]; if (e > CAP) e = CAP;
    int j = 0;
    for (; j + 4 <= e; j += 4) {                   // 4 gather streams in flight
        const int2 e0 = eb[j], e1 = eb[j + 1], e2 = eb[j + 2], e3 = eb[j + 3];
        const ushort4 y0 = *(const ushort4*)(Yb + e0.x + h0);
        const ushort4 y1 = *(const ushort4*)(Yb + e1.x + h0);
        const ushort4 y2 = *(const ushort4*)(Yb + e2.x + h0);
        const ushort4 y3 = *(const ushort4*)(Yb + e3.x + h0);
        const float v0 = __int_as_float(e0.y), v1 = __int_as_float(e1.y);
        const float v2 = __int_as_float(e2.y), v3 = __int_as_float(e3.y);
        acc.x += v0 * bf2f(y0.x) + v1 * bf2f(y1.x) + v2 * bf2f(y2.x) + v3 * bf2f(y3.x);
        acc.y += v0 * bf2f(y0.y) + v1 * bf2f(y1.y) + v2 * bf2f(y2.y) + v3 * bf2f(y3.y);
        acc.z += v0 * bf2f(y0.z) + v1 * bf2f(y1.z) + v2 * bf2f(y2.z) + v3 * bf2f(y3.z);
        acc.w += v0 * bf2f(y0.w) + v1 * bf2f(y1.w) + v2 * bf2f(y2.w) + v3 * bf2f(y3.w);
    }
    for (; j < e; ++j) {
        const int2 ed = eb[j];
        const float v = __int_as_float(ed.y);
        const ushort4 y = *(const ushort4*)(Yb + ed.x + h0);
        acc.x += v * bf2f(y.x);
        acc.y += v * bf2f(y.y);
        acc.z += v * bf2f(y.z);
        acc.w += v * bf2f(y.w);
    }

    const float a = alpha[0];
    float4 o;
    o.x = acc.x >= 0.f ? acc.x : a * acc.x;
    o.y = acc.y >= 0.f ? acc.y : a * acc.y;
    o.z = acc.z >= 0.f ? acc.z : a * acc.z;
    o.w = acc.w >= 0.f ? acc.w : a * acc.w;
    *(float4*)(out + row * H_OUT + h0) = o;
}

static inline size_t align256(size_t x) { return (x + 255) & ~(size_t)255; }

extern "C" void kernel_launch(void* const* d_in, const int* in_sizes, int n_in,
                              void* d_out, int out_size, void* d_ws, size_t ws_size,
                              hipStream_t stream) {
    const float* X     = (const float*)d_in[0];
    const int*   rows  = (const int*)d_in[1];
    const int*   cols  = (const int*)d_in[2];
    const float* vals  = (const float*)d_in[3];
    const float* W     = (const float*)d_in[4];
    const float* b     = (const float*)d_in[5];
    const float* alpha = (const float*)d_in[6];
    float* out = (float*)d_out;

    char* ws = (char*)d_ws;
    size_t off = 0;
    ushort* Xb  = (ushort*)(ws + off); off = align256(off + (size_t)MP * D_IN * 2);
    ushort* WbT = (ushort*)(ws + off); off = align256(off + (size_t)NTOT * D_IN * 2);
    ushort* Yb  = (ushort*)(ws + off); off = align256(off + (size_t)MP * NTOT * 2);
    int* cnt    = (int*)(ws + off);    off = align256(off + (size_t)N_NODES * 4);
    int2* edges = (int2*)(ws + off);   off = align256(off + (size_t)N_NODES * CAP * 8);

    hipMemsetAsync(cnt, 0, (size_t)N_NODES * 4, stream);

    cvtX_kernel<<<MP * D_IN / 4 / 256, 256, 0, stream>>>(X, Xb);
    cvtW_kernel<<<(NTOT * D_IN + 255) / 256, 256, 0, stream>>>(W, WbT);
    scatter_kernel<<<(K1H * E_EDGES + 255) / 256, 256, 0, stream>>>(rows, cols, vals, cnt, edges);
    gemm_kernel<<<196 * 4, 512, 0, stream>>>(Xb, WbT, Yb);
    spmm_kernel<<<N_NODES / 4, 256, 0, stream>>>(edges, cnt, Yb, b, alpha, out);
}

// Round 2
// 743.036 us; speedup vs baseline: 1.0522x; 1.0099x over previous
//
#include <hip/hip_runtime.h>
#include <hip/hip_bf16.h>
#include <stdint.h>

#define N_NODES 50000
#define E_EDGES 400000
#define K1H 4
#define D_IN 1280
#define H_OUT 256
#define NTOT 1024          // K1H * H_OUT (fused GEMM output width)
#define MP 50176           // N padded to 196 row-tiles of 256
#define CAP 128            // edge bucket capacity per dest row (lambda=32, overflow ~e^-60)

typedef float f32x4 __attribute__((ext_vector_type(4)));
typedef short s16x8 __attribute__((ext_vector_type(8)));

#define GLOBAL_AS __attribute__((address_space(1)))
#define LDS_AS __attribute__((address_space(3)))

__device__ __forceinline__ void g2lds16(const void* g, void* l) {
    __builtin_amdgcn_global_load_lds((const GLOBAL_AS uint32_t*)g,
                                     (LDS_AS uint32_t*)l, 16, 0, 0);
}

// fp32 -> bf16 round-nearest-even
__device__ __forceinline__ ushort f2bf(float x) {
    uint32_t u = __float_as_uint(x);
    uint32_t r = u + 0x7FFFu + ((u >> 16) & 1u);
    return (ushort)(r >> 16);
}
__device__ __forceinline__ float bf2f(ushort u) {
    return __uint_as_float(((uint32_t)u) << 16);
}

// ---- Kernel 1a: X fp32 [N,D] -> Xb bf16 [MP,D], pad rows zeroed ----
__global__ void cvtX_kernel(const float* __restrict__ X, ushort* __restrict__ Xb) {
    int i = (blockIdx.x * 256 + threadIdx.x) * 4;   // MP*D_IN = 64,225,280 < 2^31
    ushort4 o;
    if (i < N_NODES * D_IN) {
        const float4 v = *(const float4*)(X + i);
        o.x = f2bf(v.x); o.y = f2bf(v.y); o.z = f2bf(v.z); o.w = f2bf(v.w);
    } else {
        o.x = 0; o.y = 0; o.z = 0; o.w = 0;
    }
    *(ushort4*)(Xb + i) = o;
}

// ---- Kernel 1b: W [4][1280][256] fp32 -> WbT bf16 [n=k*256+h][d] (B^T layout) ----
__global__ void cvtW_kernel(const float* __restrict__ W, ushort* __restrict__ WbT) {
    int o = blockIdx.x * 256 + threadIdx.x;
    if (o >= NTOT * D_IN) return;
    int n = o / D_IN, d = o - n * D_IN;
    int k = n >> 8, h = n & 255;
    WbT[o] = f2bf(W[(k * D_IN + d) * H_OUT + h]);
}

// ---- Kernel 2: single-pass bucket scatter.  edge record = (Yb offset, val) ----
__global__ void scatter_kernel(const int* __restrict__ rows, const int* __restrict__ cols,
                               const float* __restrict__ vals, int* __restrict__ cnt,
                               int2* __restrict__ edges) {
    int i = blockIdx.x * 256 + threadIdx.x;
    if (i >= K1H * E_EDGES) return;
    int k = i / E_EDGES;                     // hop index 0..3
    int r = rows[i];
    int pos = atomicAdd(&cnt[r], 1);
    if (pos < CAP)                           // statistically never taken
        edges[(size_t)r * CAP + pos] =
            make_int2((cols[i] << 10) | (k << 8), __float_as_int(vals[i]));
}

// ---- Kernel 3: GEMM  Yb[MP,1024] = Xb[MP,1280] @ WbT^T  (bf16 MFMA, bf16 out) ----
// 256x256 tile, BK=64, 8 waves (2Mx4N, 128x64 per wave), 8-phase schedule,
// double-buffered LDS (128 KiB), counted vmcnt, and ONE barrier per phase:
//   {reads(p); stage(p); vmc; BARR(p); lgkm0; MFMA(p)}  -- trailing barrier
// removed.  Safety (verified per-phase):
//  * stage(p) writes a unit whose last ds_read was at phase <= p-2; reads(q)
//    complete at that wave's lgkm0 right after BARR(q), and every wave's
//    arrival at BARR(p-1) is ordered after its own lgkm0(p-2) -> no wave can
//    issue stage(p) before all reads(p-2) completed.
//  * in-segment overlaps reads(p)||stage(p+1) and reads(p+1)||stage(p) are
//    unit-disjoint for all 8 phases (A g0={rows 0-63,128-191}, g1=rest;
//    B g0/g1 = matching 32-col stripe groups; bufs alternate).
//  * each VMC(N) retires exactly the units read after the barrier that
//    follows it (same counts as the 2-barrier version).
// Effect: MFMA(p) and reads(p+1) share one inter-barrier segment, so the two
// waves per SIMD de-synchronize -> LDS-read issue hides under MFMA issue.
#define BARR() __builtin_amdgcn_s_barrier()
#define LGKM0() { asm volatile("s_waitcnt lgkmcnt(0)" ::: "memory"); \
                  __builtin_amdgcn_sched_barrier(0); }
#define VMC(N) asm volatile("s_waitcnt vmcnt(" #N ")" ::: "memory")

__global__ void __launch_bounds__(512, 2)
gemm_kernel(const ushort* __restrict__ Xb, const ushort* __restrict__ WbT,
            ushort* __restrict__ Yb) {
    __shared__ ushort lds[2][2][256 * 64];   // [dbuf][A=0,B=1][row*8+chunk], 128 KiB

    const int bid = blockIdx.x;               // 0 .. 783 (196 row-tiles x 4 col-tiles)
    const int xcd = bid & 7, j = bid >> 3;    // 98 blocks per XCD, contiguous tiles
    const int j2 = xcd * 98 + j;
    const int rt = j2 >> 2, ct = j2 & 3;
    const int rowBase = rt * 256, colBase = ct * 256;
    const int t = threadIdx.x;
    const int w = t >> 6, lane = t & 63;
    const int quad = lane >> 4, l16 = lane & 15;
    const int wm = w >> 2, wn = w & 3;        // 2 x 4 wave grid

    f32x4 acc[8][4] = {};
    s16x8 af[4][2];          // A frags, current mh half (reused across 2 phases)
    s16x8 bfr[2][2][2];      // B frags [nh][nt][ks], both halves held per tile

    const int kcg = (t & 7) ^ ((t >> 3) & 7);
    const ushort* pA = Xb + (rowBase + (t >> 3)) * D_IN + kcg * 8;
    const ushort* pB = WbT + (colBase + (t >> 3) + wm * 32) * D_IN + kcg * 8;

    // stage one 16KB half-tile (2 x global_load_lds per thread); LDS dst is
    // lane-linear (base + lane*16) as required by global_load_lds.
#define STAGE_A(BUF, G, KT) { _Pragma("unroll") \
    for (int r = 0; r < 2; ++r) \
        g2lds16(pA + (r * 128 + (G) * 64) * D_IN + (KT) * 64, \
                &lds[BUF][0][(t + (G) * 512 + r * 1024) * 8]); }
#define STAGE_B(BUF, G, KT) { _Pragma("unroll") \
    for (int r = 0; r < 2; ++r) \
        g2lds16(pB + (r * 128 + (G) * 32) * D_IN + (KT) * 64, \
                &lds[BUF][1][(t + wm * 256 + (G) * 256 + r * 1024) * 8]); }
#define LDA_F(BUF, MH) { _Pragma("unroll") \
    for (int mt = 0; mt < 4; ++mt) { \
        const int m = wm * 128 + (MH) * 64 + mt * 16 + l16; \
        _Pragma("unroll") for (int ks = 0; ks < 2; ++ks) \
            af[mt][ks] = *(const s16x8*)&lds[BUF][0][(m * 8 + ((ks * 4 + quad) ^ (l16 & 7))) * 8]; } }
#define LDB_F(BUF, NH) { _Pragma("unroll") \
    for (int nt = 0; nt < 2; ++nt) { \
        const int n = wn * 64 + (NH) * 32 + nt * 16 + l16; \
        _Pragma("unroll") for (int ks = 0; ks < 2; ++ks) \
            bfr[NH][nt][ks] = *(const s16x8*)&lds[BUF][1][(n * 8 + ((ks * 4 + quad) ^ (l16 & 7))) * 8]; } }
#define MMA_Q(MH, NH) { __builtin_amdgcn_s_setprio(1); \
    _Pragma("unroll") for (int mt = 0; mt < 4; ++mt) \
        _Pragma("unroll") for (int nt = 0; nt < 2; ++nt) \
            _Pragma("unroll") for (int ks = 0; ks < 2; ++ks) \
                acc[(MH) * 4 + mt][(NH) * 2 + nt] = \
                    __builtin_amdgcn_mfma_f32_16x16x32_bf16(af[mt][ks], bfr[NH][nt][ks], \
                        acc[(MH) * 4 + mt][(NH) * 2 + nt], 0, 0, 0); \
    __builtin_amdgcn_s_setprio(0); }

    // prologue: tile0 (4 units -> buf0) + tile1 Ag0,Bg0 (-> buf1); wait only for
    // tile0's first two units (4 half-tiles stay in flight), then barrier.
    STAGE_A(0, 0, 0); STAGE_B(0, 0, 0); STAGE_A(0, 1, 0); STAGE_B(0, 1, 0);
    STAGE_A(1, 0, 1); STAGE_B(1, 0, 1);
    VMC(8);
    BARR();

    // main loop: iter i computes tiles 2i (buf0, ph1-4) and 2i+1 (buf1, ph5-8).
    // stage issue order/unit: ph1 tb.Ag1, ph2 tb.Bg1, ph3 ta'.Ag0, ph4 ta'.Bg0,
    // ph5 ta'.Ag1, ph6 ta'.Bg1, ph7 tb'.Ag0, ph8 tb'.Bg0  (ta'=2i+2, tb'=2i+3).
    // counted waits: VMC(6)@ph1 covers ph2/ph3 reads, VMC(8)@ph4 covers ph5,
    // VMC(6)@ph5 covers ph6/ph7, VMC(8)@ph8 covers next ph1 — each followed by
    // the phase barrier before the protected cross-wave ds_read.
#pragma unroll 1
    for (int i = 0; i < 9; ++i) {
        const int kt0 = 2 * i;
        LDA_F(0, 0); LDB_F(0, 0); STAGE_A(1, 1, kt0 + 1); VMC(6);      // ph1
        BARR(); LGKM0(); MMA_Q(0, 0);
        LDB_F(0, 1); STAGE_B(1, 1, kt0 + 1);                           // ph2
        BARR(); LGKM0(); MMA_Q(0, 1);
        LDA_F(0, 1); STAGE_A(0, 0, kt0 + 2);                           // ph3
        BARR(); LGKM0(); MMA_Q(1, 0);
        STAGE_B(0, 0, kt0 + 2); VMC(8);                                // ph4
        BARR(); MMA_Q(1, 1);
        LDA_F(1, 0); LDB_F(1, 0); STAGE_A(0, 1, kt0 + 2); VMC(6);      // ph5
        BARR(); LGKM0(); MMA_Q(0, 0);
        LDB_F(1, 1); STAGE_B(0, 1, kt0 + 2);                           // ph6
        BARR(); LGKM0(); MMA_Q(0, 1);
        LDA_F(1, 1); STAGE_A(1, 0, kt0 + 3);                           // ph7
        BARR(); LGKM0(); MMA_Q(1, 0);
        STAGE_B(1, 0, kt0 + 3); VMC(8);                                // ph8
        BARR(); MMA_Q(1, 1);
    }

    // tail iteration: tiles 18 (buf0) and 19 (buf1); only t19.Ag1/Bg1 still need
    // staging (ph1/ph2); waits tighten since no further prefetch follows.
    LDA_F(0, 0); LDB_F(0, 0); STAGE_A(1, 1, 19); VMC(6);               // ph1
    BARR(); LGKM0(); MMA_Q(0, 0);
    LDB_F(0, 1); STAGE_B(1, 1, 19);                                    // ph2
    BARR(); LGKM0(); MMA_Q(0, 1);
    LDA_F(0, 1);                                                       // ph3
    BARR(); LGKM0(); MMA_Q(1, 0);
    VMC(4);                                                            // ph4
    BARR(); MMA_Q(1, 1);
    LDA_F(1, 0); LDB_F(1, 0); VMC(0);                                  // ph5
    BARR(); LGKM0(); MMA_Q(0, 0);
    LDB_F(1, 1);                                                       // ph6
    BARR(); LGKM0(); MMA_Q(0, 1);
    LDA_F(1, 1);                                                       // ph7
    BARR(); LGKM0(); MMA_Q(1, 0);
    MMA_Q(1, 1);                                                       // ph8

    // C/D layout: col = lane&15, row = quad*4 + reg  (m89/m91 verified)
    #pragma unroll
    for (int mh = 0; mh < 2; ++mh)
      #pragma unroll
      for (int mt = 0; mt < 4; ++mt)
        #pragma unroll
        for (int nh = 0; nh < 2; ++nh)
          #pragma unroll
          for (int nt = 0; nt < 2; ++nt) {
            const int rr = rowBase + wm * 128 + mh * 64 + mt * 16 + quad * 4;
            const int cc = colBase + wn * 64 + nh * 32 + nt * 16 + l16;
            #pragma unroll
            for (int r = 0; r < 4; ++r)
                Yb[(rr + r) * NTOT + cc] = f2bf(acc[mh * 4 + mt][nh * 2 + nt][r]);
          }
}

#undef STAGE_A
#undef STAGE_B
#undef LDA_F
#undef LDB_F
#undef MMA_Q

// ---- Kernel 4: bucket gather-SpMM + bias + PReLU.  One WAVE per dest row ----
// Lane l holds h = l*4 .. l*4+3; per edge one coalesced 512B ushort4 slice load.
__global__ void __launch_bounds__(256)
spmm_kernel(const int2* __restrict__ edges, const int* __restrict__ cnt,
            const ushort* __restrict__ Yb, const float* __restrict__ b,
            const float* __restrict__ alpha, float* __restrict__ out) {
    const int wid = threadIdx.x >> 6, lane = threadIdx.x & 63;
    const int row = blockIdx.x * 4 + wid;          // N_NODES = 12500 * 4 exactly
    const int h0 = lane * 4;

    float4 acc = make_float4(0.f, 0.f, 0.f, 0.f);
    #pragma unroll
    for (int k = 0; k < K1H; ++k) {
        const float4 bb = *(const float4*)(b + k * H_OUT + h0);
        acc.x += bb.x; acc.y += bb.y; acc.z += bb.z; acc.w += bb.w;
    }

    const int2* eb = edges + (size_t)row * CAP;
    int e = cnt[row]; if (e > CAP) e = CAP;
    int j = 0;
    for (; j + 4 <= e; j += 4) {                   // 4 gather streams in flight
        const int2 e0 = eb[j], e1 = eb[j + 1], e2 = eb[j + 2], e3 = eb[j + 3];
        const ushort4 y0 = *(const ushort4*)(Yb + e0.x + h0);
        const ushort4 y1 = *(const ushort4*)(Yb + e1.x + h0);
        const ushort4 y2 = *(const ushort4*)(Yb + e2.x + h0);
        const ushort4 y3 = *(const ushort4*)(Yb + e3.x + h0);
        const float v0 = __int_as_float(e0.y), v1 = __int_as_float(e1.y);
        const float v2 = __int_as_float(e2.y), v3 = __int_as_float(e3.y);
        acc.x += v0 * bf2f(y0.x) + v1 * bf2f(y1.x) + v2 * bf2f(y2.x) + v3 * bf2f(y3.x);
        acc.y += v0 * bf2f(y0.y) + v1 * bf2f(y1.y) + v2 * bf2f(y2.y) + v3 * bf2f(y3.y);
        acc.z += v0 * bf2f(y0.z) + v1 * bf2f(y1.z) + v2 * bf2f(y2.z) + v3 * bf2f(y3.z);
        acc.w += v0 * bf2f(y0.w) + v1 * bf2f(y1.w) + v2 * bf2f(y2.w) + v3 * bf2f(y3.w);
    }
    for (; j < e; ++j) {
        const int2 ed = eb[j];
        const float v = __int_as_float(ed.y);
        const ushort4 y = *(const ushort4*)(Yb + ed.x + h0);
        acc.x += v * bf2f(y.x);
        acc.y += v * bf2f(y.y);
        acc.z += v * bf2f(y.z);
        acc.w += v * bf2f(y.w);
    }

    const float a = alpha[0];
    float4 o;
    o.x = acc.x >= 0.f ? acc.x : a * acc.x;
    o.y = acc.y >= 0.f ? acc.y : a * acc.y;
    o.z = acc.z >= 0.f ? acc.z : a * acc.z;
    o.w = acc.w >= 0.f ? acc.w : a * acc.w;
    *(float4*)(out + row * H_OUT + h0) = o;
}

static inline size_t align256(size_t x) { return (x + 255) & ~(size_t)255; }

extern "C" void kernel_launch(void* const* d_in, const int* in_sizes, int n_in,
                              void* d_out, int out_size, void* d_ws, size_t ws_size,
                              hipStream_t stream) {
    const float* X     = (const float*)d_in[0];
    const int*   rows  = (const int*)d_in[1];
    const int*   cols  = (const int*)d_in[2];
    const float* vals  = (const float*)d_in[3];
    const float* W     = (const float*)d_in[4];
    const float* b     = (const float*)d_in[5];
    const float* alpha = (const float*)d_in[6];
    float* out = (float*)d_out;

    char* ws = (char*)d_ws;
    size_t off = 0;
    ushort* Xb  = (ushort*)(ws + off); off = align256(off + (size_t)MP * D_IN * 2);
    ushort* WbT = (ushort*)(ws + off); off = align256(off + (size_t)NTOT * D_IN * 2);
    ushort* Yb  = (ushort*)(ws + off); off = align256(off + (size_t)MP * NTOT * 2);
    int* cnt    = (int*)(ws + off);    off = align256(off + (size_t)N_NODES * 4);
    int2* edges = (int2*)(ws + off);   off = align256(off + (size_t)N_NODES * CAP * 8);

    hipMemsetAsync(cnt, 0, (size_t)N_NODES * 4, stream);

    cvtX_kernel<<<MP * D_IN / 4 / 256, 256, 0, stream>>>(X, Xb);
    cvtW_kernel<<<(NTOT * D_IN + 255) / 256, 256, 0, stream>>>(W, WbT);
    scatter_kernel<<<(K1H * E_EDGES + 255) / 256, 256, 0, stream>>>(rows, cols, vals, cnt, edges);
    gemm_kernel<<<196 * 4, 512, 0, stream>>>(Xb, WbT, Yb);
    spmm_kernel<<<N_NODES / 4, 256, 0, stream>>>(edges, cnt, Yb, b, alpha, out);
}